// Round 1
// baseline (309.527 us; speedup 1.0000x reference)
//
#include <hip/hip_runtime.h>

typedef __bf16 bf16;
typedef __bf16 bf16x8 __attribute__((ext_vector_type(8)));
typedef __bf16 bf16x4 __attribute__((ext_vector_type(4)));
typedef float  f32x4  __attribute__((ext_vector_type(4)));

#define CDIM   512
#define NPOS   1024
#define NBATCH 16
#define MTOT   (NBATCH * NPOS)        // 16384 total rows
#define WELEMS (CDIM * CDIM)          // 262144 elems per weight

// ---------------- workspace layout (bytes) ----------------
// wt:  4 x [512][512] bf16 (transposed weights q,k,v,p)   2 MiB
// xn:  [16384][512] bf16   (normalized input; reused as O after PV)
// q,k: [16384][512] bf16
// vt:  [16][512][1024] bf16 (V transposed per batch)
// s:   [16][1024][1024] f32 (scores)
// p:   [16][1024][1024] bf16 (attn probs)
#define OFF_WT  ((size_t)0)
#define OFF_XN  ((size_t)(2 * 1024 * 1024))
#define OFF_Q   (OFF_XN + (size_t)MTOT * CDIM * 2)
#define OFF_K   (OFF_Q  + (size_t)MTOT * CDIM * 2)
#define OFF_VT  (OFF_K  + (size_t)MTOT * CDIM * 2)
#define OFF_S   (OFF_VT + (size_t)MTOT * CDIM * 2)
#define OFF_P   (OFF_S  + (size_t)NBATCH * NPOS * NPOS * 4)
#define OFF_O   OFF_XN   // xn dead after QKV GEMMs; reuse for O

// ---------------- weight transpose + cast ----------------
__global__ __launch_bounds__(256) void transpose_cast(
    const float* __restrict__ w0, const float* __restrict__ w1,
    const float* __restrict__ w2, const float* __restrict__ w3,
    bf16* __restrict__ wt)
{
    __shared__ bf16 tile[32][33];
    int z = blockIdx.z;
    const float* W = (z == 0) ? w0 : (z == 1) ? w1 : (z == 2) ? w2 : w3;
    bf16* out = wt + (size_t)z * WELEMS;
    int bx = blockIdx.x * 32;   // output-col base (co)
    int by = blockIdx.y * 32;   // input-row base (ci)
    int tx = threadIdx.x & 31, ty = threadIdx.x >> 5;   // 32 x 8
    #pragma unroll
    for (int i = ty; i < 32; i += 8)
        tile[i][tx] = (bf16)W[(size_t)(by + i) * CDIM + bx + tx];  // coalesced read
    __syncthreads();
    #pragma unroll
    for (int i = ty; i < 32; i += 8)
        out[(size_t)(bx + i) * CDIM + by + tx] = tile[tx][i];      // coalesced write
}

// ---------------- GroupNorm -> bf16 ----------------
__global__ __launch_bounds__(256) void groupnorm_kernel(
    const float* __restrict__ x, const float* __restrict__ gamma,
    const float* __restrict__ beta, bf16* __restrict__ xn)
{
    int b = blockIdx.x >> 5;       // 16 batches
    int g = blockIdx.x & 31;       // 32 groups, 16 channels each
    const float* xb = x + (size_t)b * NPOS * CDIM;
    int t = threadIdx.x, lane = t & 63, wid = t >> 6;

    float s = 0.f, s2 = 0.f;
    // 1024 positions x 16 channels = 4096 float4s
    for (int i = t; i < 4096; i += 256) {
        int n = i >> 2, c4 = i & 3;
        const float4 v = *(const float4*)&xb[n * CDIM + g * 16 + c4 * 4];
        s  += v.x + v.y + v.z + v.w;
        s2 += v.x * v.x + v.y * v.y + v.z * v.z + v.w * v.w;
    }
    #pragma unroll
    for (int o = 32; o; o >>= 1) { s += __shfl_xor(s, o); s2 += __shfl_xor(s2, o); }
    __shared__ float rs[4], rs2[4];
    if (lane == 0) { rs[wid] = s; rs2[wid] = s2; }
    __syncthreads();
    float S  = rs[0] + rs[1] + rs[2] + rs[3];
    float S2 = rs2[0] + rs2[1] + rs2[2] + rs2[3];
    const float inv_n = 1.f / 16384.f;
    float mean = S * inv_n;
    float var  = S2 * inv_n - mean * mean;
    float rstd = rsqrtf(var + 1e-3f);

    bf16* xnb = xn + (size_t)b * NPOS * CDIM;
    for (int i = t; i < 4096; i += 256) {
        int n = i >> 2, c4 = i & 3;
        int c = g * 16 + c4 * 4;
        const float4 v = *(const float4*)&xb[n * CDIM + c];
        bf16x4 o;
        o.x = (bf16)(((v.x - mean) * rstd) * gamma[c + 0] + beta[c + 0]);
        o.y = (bf16)(((v.y - mean) * rstd) * gamma[c + 1] + beta[c + 1]);
        o.z = (bf16)(((v.z - mean) * rstd) * gamma[c + 2] + beta[c + 2]);
        o.w = (bf16)(((v.w - mean) * rstd) * gamma[c + 3] + beta[c + 3]);
        *(bf16x4*)&xnb[n * CDIM + c] = o;
    }
}

// ---------------- MFMA tile GEMM (NT: C[i,j] = sum_k A[i,k]*B[j,k]) ----------------
// MODE 0: bf16 write  C[row*ldc+col] = (acc+bias)*scale
// MODE 1: bf16 transposed write (Vt): b=row>>10, n=row&1023 -> C[b*strideC + col*ldc + n]
// MODE 2: f32 write (scores)
// MODE 3: f32 + residual (final output)
#define BM 128
#define BN 128
#define BK 32
#define LDSS 40   // padded LDS row stride in elems (80 B): 2-way max bank conflict

template<int MODE>
__global__ __launch_bounds__(256) void gemm_nt(
    const bf16* __restrict__ A, int lda, long strideA,
    const bf16* __restrict__ B, int ldb, long strideB,
    const float* __restrict__ bias, float scale,
    void* __restrict__ Cp, int ldc, long strideC,
    const float* __restrict__ resid, int K)
{
    __shared__ bf16 lsa[BM * LDSS];
    __shared__ bf16 lsb[BN * LDSS];
    const int z = blockIdx.z;
    A += (size_t)z * strideA;
    B += (size_t)z * strideB;
    const int bm = blockIdx.x * BM;
    const int bn = blockIdx.y * BN;
    const int t = threadIdx.x;
    const int lane = t & 63;
    const int wid = t >> 6;
    const int wr = (wid >> 1) * 64;   // wave row offset in tile
    const int wc = (wid & 1) * 64;    // wave col offset in tile
    const int lr = lane & 15;         // fragment row (A) / col (B) / col (D)
    const int ks = lane >> 4;         // k-slot (elements ks*8..ks*8+7)

    f32x4 acc[4][4] = {};

    for (int k0 = 0; k0 < K; k0 += BK) {
        #pragma unroll
        for (int i = 0; i < 2; i++) {
            int e = (i * 256 + t) * 8;       // element index in 128x32 tile
            int r = e >> 5, c = e & 31;
            *(bf16x8*)&lsa[r * LDSS + c] = *(const bf16x8*)&A[(size_t)(bm + r) * lda + k0 + c];
            *(bf16x8*)&lsb[r * LDSS + c] = *(const bf16x8*)&B[(size_t)(bn + r) * ldb + k0 + c];
        }
        __syncthreads();
        bf16x8 af[4], bfr[4];
        #pragma unroll
        for (int m = 0; m < 4; m++)
            af[m] = *(const bf16x8*)&lsa[(wr + m * 16 + lr) * LDSS + ks * 8];
        #pragma unroll
        for (int n = 0; n < 4; n++)
            bfr[n] = *(const bf16x8*)&lsb[(wc + n * 16 + lr) * LDSS + ks * 8];
        #pragma unroll
        for (int m = 0; m < 4; m++)
            #pragma unroll
            for (int n = 0; n < 4; n++)
                acc[m][n] = __builtin_amdgcn_mfma_f32_16x16x32_bf16(af[m], bfr[n], acc[m][n], 0, 0, 0);
        __syncthreads();
    }

    // Epilogue. C/D layout (verified m89): col = lane&15, row = (lane>>4)*4 + reg.
    #pragma unroll
    for (int m = 0; m < 4; m++) {
        #pragma unroll
        for (int n = 0; n < 4; n++) {
            const int row0 = bm + wr + m * 16 + ks * 4;
            const int col  = bn + wc + n * 16 + lr;
            const float bv = bias ? bias[col] : 0.f;
            #pragma unroll
            for (int r = 0; r < 4; r++) {
                const int rr = row0 + r;
                const float v = (acc[m][n][r] + bv) * scale;
                if (MODE == 0) {
                    ((bf16*)Cp)[(size_t)z * strideC + (size_t)rr * ldc + col] = (bf16)v;
                } else if (MODE == 1) {
                    const int bb = rr >> 10, nn = rr & 1023;
                    ((bf16*)Cp)[(size_t)bb * strideC + (size_t)col * ldc + nn] = (bf16)v;
                } else if (MODE == 2) {
                    ((float*)Cp)[(size_t)z * strideC + (size_t)rr * ldc + col] = v;
                } else {
                    const size_t idx = (size_t)rr * ldc + col;
                    ((float*)Cp)[idx] = v + resid[idx];
                }
            }
        }
    }
}

// ---------------- row softmax: S (f32, 1024 wide) -> P (bf16) ----------------
__global__ __launch_bounds__(256) void softmax_rows(
    const float* __restrict__ S, bf16* __restrict__ P)
{
    const size_t row = blockIdx.x;          // 16384 rows
    const float* s = S + row * NPOS;
    const int t = threadIdx.x, lane = t & 63, wid = t >> 6;
    float4 v = *(const float4*)&s[t * 4];

    float m = fmaxf(fmaxf(v.x, v.y), fmaxf(v.z, v.w));
    #pragma unroll
    for (int o = 32; o; o >>= 1) m = fmaxf(m, __shfl_xor(m, o));
    __shared__ float rmax[4], rsum[4];
    if (lane == 0) rmax[wid] = m;
    __syncthreads();
    m = fmaxf(fmaxf(rmax[0], rmax[1]), fmaxf(rmax[2], rmax[3]));

    float e0 = __expf(v.x - m), e1 = __expf(v.y - m);
    float e2 = __expf(v.z - m), e3 = __expf(v.w - m);
    float sum = e0 + e1 + e2 + e3;
    #pragma unroll
    for (int o = 32; o; o >>= 1) sum += __shfl_xor(sum, o);
    if (lane == 0) rsum[wid] = sum;
    __syncthreads();
    sum = rsum[0] + rsum[1] + rsum[2] + rsum[3];
    const float inv = 1.f / sum;

    bf16x4 o;
    o.x = (bf16)(e0 * inv); o.y = (bf16)(e1 * inv);
    o.z = (bf16)(e2 * inv); o.w = (bf16)(e3 * inv);
    *(bf16x4*)&P[row * NPOS + t * 4] = o;
}

// ---------------- launch ----------------
extern "C" void kernel_launch(void* const* d_in, const int* in_sizes, int n_in,
                              void* d_out, int out_size, void* d_ws, size_t ws_size,
                              hipStream_t stream) {
    const float* x     = (const float*)d_in[0];
    const float* gamma = (const float*)d_in[1];
    const float* beta  = (const float*)d_in[2];
    const float* wq    = (const float*)d_in[3];
    const float* bq    = (const float*)d_in[4];
    const float* wk    = (const float*)d_in[5];
    const float* bk    = (const float*)d_in[6];
    const float* wv    = (const float*)d_in[7];
    const float* bv    = (const float*)d_in[8];
    const float* wp    = (const float*)d_in[9];
    const float* bp    = (const float*)d_in[10];

    char* ws = (char*)d_ws;
    bf16*  wt = (bf16*)(ws + OFF_WT);
    bf16*  xn = (bf16*)(ws + OFF_XN);
    bf16*  Q  = (bf16*)(ws + OFF_Q);
    bf16*  Km = (bf16*)(ws + OFF_K);
    bf16*  Vt = (bf16*)(ws + OFF_VT);
    float* Sc = (float*)(ws + OFF_S);
    bf16*  P  = (bf16*)(ws + OFF_P);
    bf16*  O  = (bf16*)(ws + OFF_O);

    transpose_cast<<<dim3(16, 16, 4), 256, 0, stream>>>(wq, wk, wv, wp, wt);
    groupnorm_kernel<<<dim3(512), 256, 0, stream>>>(x, gamma, beta, xn);

    const float qscale = 0.04419417382415922f;  // 512^-0.5 folded into Q
    // Q = (xn @ wq + bq) * qscale   [16384,512]
    gemm_nt<0><<<dim3(128, 4, 1), 256, 0, stream>>>(
        xn, CDIM, 0, wt + 0 * WELEMS, CDIM, 0, bq, qscale, Q, CDIM, 0, nullptr, CDIM);
    // K = xn @ wk + bk
    gemm_nt<0><<<dim3(128, 4, 1), 256, 0, stream>>>(
        xn, CDIM, 0, wt + 1 * WELEMS, CDIM, 0, bk, 1.f, Km, CDIM, 0, nullptr, CDIM);
    // Vt[b,c,n] = (xn @ wv + bv)^T
    gemm_nt<1><<<dim3(128, 4, 1), 256, 0, stream>>>(
        xn, CDIM, 0, wt + 2 * WELEMS, CDIM, 0, bv, 1.f, Vt, NPOS, (long)CDIM * NPOS, nullptr, CDIM);
    // S[b] = Q[b] @ K[b]^T   [1024,1024] f32
    gemm_nt<2><<<dim3(8, 8, 16), 256, 0, stream>>>(
        Q, CDIM, (long)NPOS * CDIM, Km, CDIM, (long)NPOS * CDIM,
        nullptr, 1.f, Sc, NPOS, (long)NPOS * NPOS, nullptr, CDIM);
    // P = softmax(S) -> bf16
    softmax_rows<<<dim3(NBATCH * NPOS), 256, 0, stream>>>(Sc, P);
    // O[b] = P[b] @ V[b]  (NT against Vt)   [1024,512] bf16
    gemm_nt<0><<<dim3(8, 4, 16), 256, 0, stream>>>(
        P, NPOS, (long)NPOS * NPOS, Vt, NPOS, (long)CDIM * NPOS,
        nullptr, 1.f, O, CDIM, (long)NPOS * CDIM, nullptr, NPOS);
    // out = O @ wp + bp + x   [16384,512] f32
    gemm_nt<3><<<dim3(128, 4, 1), 256, 0, stream>>>(
        O, CDIM, 0, wt + 3 * WELEMS, CDIM, 0, bp, 1.f, d_out, CDIM, 0, x, CDIM);
}

// Round 2
// 297.033 us; speedup vs baseline: 1.0421x; 1.0421x over previous
//
#include <hip/hip_runtime.h>

typedef __bf16 bf16;
typedef __bf16 bf16x8 __attribute__((ext_vector_type(8)));
typedef __bf16 bf16x4 __attribute__((ext_vector_type(4)));
typedef float  f32x4  __attribute__((ext_vector_type(4)));

#define CDIM   512
#define NPOS   1024
#define NBATCH 16
#define MTOT   (NBATCH * NPOS)        // 16384 total rows
#define WELEMS (CDIM * CDIM)          // 262144 elems per weight

// ---------------- workspace layout (bytes) ----------------
#define OFF_WT  ((size_t)0)
#define OFF_XN  ((size_t)(2 * 1024 * 1024))
#define OFF_Q   (OFF_XN + (size_t)MTOT * CDIM * 2)
#define OFF_K   (OFF_Q  + (size_t)MTOT * CDIM * 2)
#define OFF_VT  (OFF_K  + (size_t)MTOT * CDIM * 2)
#define OFF_S   (OFF_VT + (size_t)MTOT * CDIM * 2)
#define OFF_P   (OFF_S  + (size_t)NBATCH * NPOS * NPOS * 4)
#define OFF_O   OFF_XN   // xn dead after QKV GEMMs; reuse for O

// async global->LDS, 16B per lane. LDS dest must be wave-uniform base + lane*16.
__device__ __forceinline__ void gload16(const bf16* g, bf16* l) {
    __builtin_amdgcn_global_load_lds(
        (const __attribute__((address_space(1))) void*)g,
        (__attribute__((address_space(3))) void*)l, 16, 0, 0);
}

// ---------------- weight transpose + cast ----------------
__global__ __launch_bounds__(256) void transpose_cast(
    const float* __restrict__ w0, const float* __restrict__ w1,
    const float* __restrict__ w2, const float* __restrict__ w3,
    bf16* __restrict__ wt)
{
    __shared__ bf16 tile[32][33];
    int z = blockIdx.z;
    const float* W = (z == 0) ? w0 : (z == 1) ? w1 : (z == 2) ? w2 : w3;
    bf16* out = wt + (size_t)z * WELEMS;
    int bx = blockIdx.x * 32;   // output-col base (co)
    int by = blockIdx.y * 32;   // input-row base (ci)
    int tx = threadIdx.x & 31, ty = threadIdx.x >> 5;   // 32 x 8
    #pragma unroll
    for (int i = ty; i < 32; i += 8)
        tile[i][tx] = (bf16)W[(size_t)(by + i) * CDIM + bx + tx];  // coalesced read
    __syncthreads();
    #pragma unroll
    for (int i = ty; i < 32; i += 8)
        out[(size_t)(bx + i) * CDIM + by + tx] = tile[tx][i];      // coalesced write
}

// ---------------- GroupNorm -> bf16 ----------------
__global__ __launch_bounds__(256) void groupnorm_kernel(
    const float* __restrict__ x, const float* __restrict__ gamma,
    const float* __restrict__ beta, bf16* __restrict__ xn)
{
    int b = blockIdx.x >> 5;       // 16 batches
    int g = blockIdx.x & 31;       // 32 groups, 16 channels each
    const float* xb = x + (size_t)b * NPOS * CDIM;
    int t = threadIdx.x, lane = t & 63, wid = t >> 6;

    float s = 0.f, s2 = 0.f;
    for (int i = t; i < 4096; i += 256) {
        int n = i >> 2, c4 = i & 3;
        const float4 v = *(const float4*)&xb[n * CDIM + g * 16 + c4 * 4];
        s  += v.x + v.y + v.z + v.w;
        s2 += v.x * v.x + v.y * v.y + v.z * v.z + v.w * v.w;
    }
    #pragma unroll
    for (int o = 32; o; o >>= 1) { s += __shfl_xor(s, o); s2 += __shfl_xor(s2, o); }
    __shared__ float rs[4], rs2[4];
    if (lane == 0) { rs[wid] = s; rs2[wid] = s2; }
    __syncthreads();
    float S  = rs[0] + rs[1] + rs[2] + rs[3];
    float S2 = rs2[0] + rs2[1] + rs2[2] + rs2[3];
    const float inv_n = 1.f / 16384.f;
    float mean = S * inv_n;
    float var  = S2 * inv_n - mean * mean;
    float rstd = rsqrtf(var + 1e-3f);

    bf16* xnb = xn + (size_t)b * NPOS * CDIM;
    for (int i = t; i < 4096; i += 256) {
        int n = i >> 2, c4 = i & 3;
        int c = g * 16 + c4 * 4;
        const float4 v = *(const float4*)&xb[n * CDIM + c];
        bf16x4 o;
        o.x = (bf16)(((v.x - mean) * rstd) * gamma[c + 0] + beta[c + 0]);
        o.y = (bf16)(((v.y - mean) * rstd) * gamma[c + 1] + beta[c + 1]);
        o.z = (bf16)(((v.z - mean) * rstd) * gamma[c + 2] + beta[c + 2]);
        o.w = (bf16)(((v.w - mean) * rstd) * gamma[c + 3] + beta[c + 3]);
        *(bf16x4*)&xnb[n * CDIM + c] = o;
    }
}

// ---------------- MFMA tile GEMM (NT: C[i,j] = sum_k A[i,k]*B[j,k]) ----------------
// m97 structure: global_load_lds (16B) into LINEAR LDS [128][32], 2-barrier loop.
// MODE 0: bf16 write  C = (acc+bias)*scale
// MODE 1: bf16 transposed write (Vt): b=row>>10, n=row&1023 -> C[b*strideC + col*ldc + n]
// MODE 2: f32 write (scores)
// MODE 3: f32 + residual (final output)
#define BM 128
#define BN 128
#define BK 32

template<int MODE>
__global__ __launch_bounds__(256) void gemm_nt(
    const bf16* __restrict__ A, int lda, long strideA,
    const bf16* __restrict__ B, int ldb, long strideB,
    const float* __restrict__ bias, float scale,
    void* __restrict__ Cp, int ldc, long strideC,
    const float* __restrict__ resid, int K)
{
    __shared__ __align__(16) bf16 lsa[BM * BK];
    __shared__ __align__(16) bf16 lsb[BN * BK];
    const int z = blockIdx.z;
    A += (size_t)z * strideA;
    B += (size_t)z * strideB;
    const int bm = blockIdx.x * BM;
    const int bn = blockIdx.y * BN;
    const int t = threadIdx.x;
    const int lane = t & 63;
    const int wid = t >> 6;
    const int wr = (wid >> 1) * 64;   // wave row offset in tile
    const int wc = (wid & 1) * 64;    // wave col offset in tile
    const int lr = lane & 15;         // fragment row (A) / col (B/D)
    const int ks = lane >> 4;         // k-slot (elements ks*8..ks*8+7)

    // staging geometry: chunk ci covers row r=ci>>2, cols (ci&3)*8..+7 (16B)
    const int ci0 = t;                // first 256 chunks
    const int r0 = ci0 >> 2, c0 = (ci0 & 3) * 8;
    const int ci1 = t + 256;          // second 256 chunks
    const int r1 = ci1 >> 2, c1 = (ci1 & 3) * 8;

    f32x4 acc[4][4] = {};

    for (int k0 = 0; k0 < K; k0 += BK) {
        gload16(&A[(size_t)(bm + r0) * lda + k0 + c0], &lsa[ci0 * 8]);
        gload16(&A[(size_t)(bm + r1) * lda + k0 + c1], &lsa[ci1 * 8]);
        gload16(&B[(size_t)(bn + r0) * ldb + k0 + c0], &lsb[ci0 * 8]);
        gload16(&B[(size_t)(bn + r1) * ldb + k0 + c1], &lsb[ci1 * 8]);
        __syncthreads();   // compiler drains vmcnt before barrier
        bf16x8 af[4], bfr[4];
        #pragma unroll
        for (int m = 0; m < 4; m++)
            af[m] = *(const bf16x8*)&lsa[(wr + m * 16 + lr) * BK + ks * 8];
        #pragma unroll
        for (int n = 0; n < 4; n++)
            bfr[n] = *(const bf16x8*)&lsb[(wc + n * 16 + lr) * BK + ks * 8];
        #pragma unroll
        for (int m = 0; m < 4; m++)
            #pragma unroll
            for (int n = 0; n < 4; n++)
                acc[m][n] = __builtin_amdgcn_mfma_f32_16x16x32_bf16(af[m], bfr[n], acc[m][n], 0, 0, 0);
        __syncthreads();
    }

    // Epilogue. C/D layout (m89): col = lane&15, row = (lane>>4)*4 + reg.
    #pragma unroll
    for (int m = 0; m < 4; m++) {
        #pragma unroll
        for (int n = 0; n < 4; n++) {
            const int row0 = bm + wr + m * 16 + ks * 4;
            const int col  = bn + wc + n * 16 + lr;
            const float bv = bias ? bias[col] : 0.f;
            #pragma unroll
            for (int r = 0; r < 4; r++) {
                const int rr = row0 + r;
                const float v = (acc[m][n][r] + bv) * scale;
                if (MODE == 0) {
                    ((bf16*)Cp)[(size_t)z * strideC + (size_t)rr * ldc + col] = (bf16)v;
                } else if (MODE == 1) {
                    const int bb = rr >> 10, nn = rr & 1023;
                    ((bf16*)Cp)[(size_t)bb * strideC + (size_t)col * ldc + nn] = (bf16)v;
                } else if (MODE == 2) {
                    ((float*)Cp)[(size_t)z * strideC + (size_t)rr * ldc + col] = v;
                } else {
                    const size_t idx = (size_t)rr * ldc + col;
                    ((float*)Cp)[idx] = v + resid[idx];
                }
            }
        }
    }
}

// ---------------- row softmax: S (f32, 1024 wide) -> P (bf16) ----------------
__global__ __launch_bounds__(256) void softmax_rows(
    const float* __restrict__ S, bf16* __restrict__ P)
{
    const size_t row = blockIdx.x;          // 16384 rows
    const float* s = S + row * NPOS;
    const int t = threadIdx.x, lane = t & 63, wid = t >> 6;
    float4 v = *(const float4*)&s[t * 4];

    float m = fmaxf(fmaxf(v.x, v.y), fmaxf(v.z, v.w));
    #pragma unroll
    for (int o = 32; o; o >>= 1) m = fmaxf(m, __shfl_xor(m, o));
    __shared__ float rmax[4], rsum[4];
    if (lane == 0) rmax[wid] = m;
    __syncthreads();
    m = fmaxf(fmaxf(rmax[0], rmax[1]), fmaxf(rmax[2], rmax[3]));

    float e0 = __expf(v.x - m), e1 = __expf(v.y - m);
    float e2 = __expf(v.z - m), e3 = __expf(v.w - m);
    float sum = e0 + e1 + e2 + e3;
    #pragma unroll
    for (int o = 32; o; o >>= 1) sum += __shfl_xor(sum, o);
    if (lane == 0) rsum[wid] = sum;
    __syncthreads();
    sum = rsum[0] + rsum[1] + rsum[2] + rsum[3];
    const float inv = 1.f / sum;

    bf16x4 o;
    o.x = (bf16)(e0 * inv); o.y = (bf16)(e1 * inv);
    o.z = (bf16)(e2 * inv); o.w = (bf16)(e3 * inv);
    *(bf16x4*)&P[row * NPOS + t * 4] = o;
}

// ---------------- launch ----------------
extern "C" void kernel_launch(void* const* d_in, const int* in_sizes, int n_in,
                              void* d_out, int out_size, void* d_ws, size_t ws_size,
                              hipStream_t stream) {
    const float* x     = (const float*)d_in[0];
    const float* gamma = (const float*)d_in[1];
    const float* beta  = (const float*)d_in[2];
    const float* wq    = (const float*)d_in[3];
    const float* bq    = (const float*)d_in[4];
    const float* wk    = (const float*)d_in[5];
    const float* bk    = (const float*)d_in[6];
    const float* wv    = (const float*)d_in[7];
    const float* bv    = (const float*)d_in[8];
    const float* wp    = (const float*)d_in[9];
    const float* bp    = (const float*)d_in[10];

    char* ws = (char*)d_ws;
    bf16*  wt = (bf16*)(ws + OFF_WT);
    bf16*  xn = (bf16*)(ws + OFF_XN);
    bf16*  Q  = (bf16*)(ws + OFF_Q);
    bf16*  Km = (bf16*)(ws + OFF_K);
    bf16*  Vt = (bf16*)(ws + OFF_VT);
    float* Sc = (float*)(ws + OFF_S);
    bf16*  P  = (bf16*)(ws + OFF_P);
    bf16*  O  = (bf16*)(ws + OFF_O);

    transpose_cast<<<dim3(16, 16, 4), 256, 0, stream>>>(wq, wk, wv, wp, wt);
    groupnorm_kernel<<<dim3(512), 256, 0, stream>>>(x, gamma, beta, xn);

    const float qscale = 0.04419417382415922f;  // 512^-0.5 folded into Q
    // Q = (xn @ wq + bq) * qscale   [16384,512]
    gemm_nt<0><<<dim3(128, 4, 1), 256, 0, stream>>>(
        xn, CDIM, 0, wt + 0 * WELEMS, CDIM, 0, bq, qscale, Q, CDIM, 0, nullptr, CDIM);
    // K = xn @ wk + bk
    gemm_nt<0><<<dim3(128, 4, 1), 256, 0, stream>>>(
        xn, CDIM, 0, wt + 1 * WELEMS, CDIM, 0, bk, 1.f, Km, CDIM, 0, nullptr, CDIM);
    // Vt[b,c,n] = (xn @ wv + bv)^T
    gemm_nt<1><<<dim3(128, 4, 1), 256, 0, stream>>>(
        xn, CDIM, 0, wt + 2 * WELEMS, CDIM, 0, bv, 1.f, Vt, NPOS, (long)CDIM * NPOS, nullptr, CDIM);
    // S[b] = Q[b] @ K[b]^T   [1024,1024] f32
    gemm_nt<2><<<dim3(8, 8, 16), 256, 0, stream>>>(
        Q, CDIM, (long)NPOS * CDIM, Km, CDIM, (long)NPOS * CDIM,
        nullptr, 1.f, Sc, NPOS, (long)NPOS * NPOS, nullptr, CDIM);
    // P = softmax(S) -> bf16
    softmax_rows<<<dim3(NBATCH * NPOS), 256, 0, stream>>>(Sc, P);
    // O[b] = P[b] @ V[b]  (NT against Vt)   [1024,512] bf16
    gemm_nt<0><<<dim3(8, 4, 16), 256, 0, stream>>>(
        P, NPOS, (long)NPOS * NPOS, Vt, NPOS, (long)CDIM * NPOS,
        nullptr, 1.f, O, CDIM, (long)NPOS * CDIM, nullptr, NPOS);
    // out = O @ wp + bp + x   [16384,512] f32
    gemm_nt<3><<<dim3(128, 4, 1), 256, 0, stream>>>(
        O, CDIM, 0, wt + 3 * WELEMS, CDIM, 0, bp, 1.f, d_out, CDIM, 0, x, CDIM);
}

// Round 3
// 261.316 us; speedup vs baseline: 1.1845x; 1.1367x over previous
//
#include <hip/hip_runtime.h>

typedef __bf16 bf16;
typedef __bf16 bf16x8 __attribute__((ext_vector_type(8)));
typedef __bf16 bf16x4 __attribute__((ext_vector_type(4)));
typedef float  f32x4  __attribute__((ext_vector_type(4)));

#define CDIM   512
#define NPOS   1024
#define NBATCH 16
#define MTOT   (NBATCH * NPOS)
#define WELEMS (CDIM * CDIM)

// ---------------- workspace layout (bytes) ----------------
#define OFF_WT  ((size_t)0)
#define OFF_XN  ((size_t)(2 * 1024 * 1024))
#define OFF_Q   (OFF_XN + (size_t)MTOT * CDIM * 2)
#define OFF_K   (OFF_Q  + (size_t)MTOT * CDIM * 2)
#define OFF_VT  (OFF_K  + (size_t)MTOT * CDIM * 2)
#define OFF_O   OFF_XN   // xn dead after QKV GEMM; reuse for O

// async global->LDS, 16B per lane. LDS dest must be wave-uniform base + lane*16.
__device__ __forceinline__ void gload16(const bf16* g, bf16* l) {
    __builtin_amdgcn_global_load_lds(
        (const __attribute__((address_space(1))) void*)g,
        (__attribute__((address_space(3))) void*)l, 16, 0, 0);
}

__device__ __forceinline__ unsigned int pk2(float lo, float hi) {
    union { bf16 h; unsigned short s; } a, c;
    a.h = (bf16)lo; c.h = (bf16)hi;
    return (unsigned int)a.s | ((unsigned int)c.s << 16);
}

// ---------------- weight transpose + cast ----------------
__global__ __launch_bounds__(256) void transpose_cast(
    const float* __restrict__ w0, const float* __restrict__ w1,
    const float* __restrict__ w2, const float* __restrict__ w3,
    bf16* __restrict__ wt)
{
    __shared__ bf16 tile[32][33];
    int z = blockIdx.z;
    const float* W = (z == 0) ? w0 : (z == 1) ? w1 : (z == 2) ? w2 : w3;
    bf16* out = wt + (size_t)z * WELEMS;
    int bx = blockIdx.x * 32;
    int by = blockIdx.y * 32;
    int tx = threadIdx.x & 31, ty = threadIdx.x >> 5;
    #pragma unroll
    for (int i = ty; i < 32; i += 8)
        tile[i][tx] = (bf16)W[(size_t)(by + i) * CDIM + bx + tx];
    __syncthreads();
    #pragma unroll
    for (int i = ty; i < 32; i += 8)
        out[(size_t)(bx + i) * CDIM + by + tx] = tile[tx][i];
}

// ---------------- GroupNorm -> bf16 ----------------
__global__ __launch_bounds__(256) void groupnorm_kernel(
    const float* __restrict__ x, const float* __restrict__ gamma,
    const float* __restrict__ beta, bf16* __restrict__ xn)
{
    int b = blockIdx.x >> 5;
    int g = blockIdx.x & 31;
    const float* xb = x + (size_t)b * NPOS * CDIM;
    int t = threadIdx.x, lane = t & 63, wid = t >> 6;

    float s = 0.f, s2 = 0.f;
    for (int i = t; i < 4096; i += 256) {
        int n = i >> 2, c4 = i & 3;
        const float4 v = *(const float4*)&xb[n * CDIM + g * 16 + c4 * 4];
        s  += v.x + v.y + v.z + v.w;
        s2 += v.x * v.x + v.y * v.y + v.z * v.z + v.w * v.w;
    }
    #pragma unroll
    for (int o = 32; o; o >>= 1) { s += __shfl_xor(s, o); s2 += __shfl_xor(s2, o); }
    __shared__ float rs[4], rs2[4];
    if (lane == 0) { rs[wid] = s; rs2[wid] = s2; }
    __syncthreads();
    float S  = rs[0] + rs[1] + rs[2] + rs[3];
    float S2 = rs2[0] + rs2[1] + rs2[2] + rs2[3];
    const float inv_n = 1.f / 16384.f;
    float mean = S * inv_n;
    float var  = S2 * inv_n - mean * mean;
    float rstd = rsqrtf(var + 1e-3f);

    bf16* xnb = xn + (size_t)b * NPOS * CDIM;
    for (int i = t; i < 4096; i += 256) {
        int n = i >> 2, c4 = i & 3;
        int c = g * 16 + c4 * 4;
        const float4 v = *(const float4*)&xb[n * CDIM + c];
        bf16x4 o;
        o[0] = (bf16)(((v.x - mean) * rstd) * gamma[c + 0] + beta[c + 0]);
        o[1] = (bf16)(((v.y - mean) * rstd) * gamma[c + 1] + beta[c + 1]);
        o[2] = (bf16)(((v.z - mean) * rstd) * gamma[c + 2] + beta[c + 2]);
        o[3] = (bf16)(((v.w - mean) * rstd) * gamma[c + 3] + beta[c + 3]);
        *(bf16x4*)&xnb[n * CDIM + c] = o;
    }
}

// ---------------- fused QKV GEMM: [16384,512] x [512,1536] ----------------
// B = wt (concat wq^T,wk^T,wv^T rows 0..1535). Region by blockIdx.y>>2:
//   0: Q = (acc+bq)*qscale -> Q[r][c]
//   1: K = acc+bk          -> K[r][c]
//   2: V = acc+bv          -> Vt[b][c][n]  (transposed write)
#define BM 128
#define BN 128
#define BK 32

__global__ __launch_bounds__(256) void gemm_qkv(
    const bf16* __restrict__ A, const bf16* __restrict__ Bw,
    const float* __restrict__ bq, const float* __restrict__ bk,
    const float* __restrict__ bv, float qscale,
    bf16* __restrict__ Qo, bf16* __restrict__ Ko, bf16* __restrict__ Vto)
{
    __shared__ __align__(16) bf16 lsa[BM * BK];
    __shared__ __align__(16) bf16 lsb[BN * BK];
    const int bm = blockIdx.x * BM;
    const int bnG = blockIdx.y * BN;          // global col in [0,1536)
    const int region = blockIdx.y >> 2;       // 0=Q 1=K 2=V
    const int t = threadIdx.x;
    const int lane = t & 63;
    const int wid = t >> 6;
    const int wr = (wid >> 1) * 64;
    const int wc = (wid & 1) * 64;
    const int lr = lane & 15;
    const int ks = lane >> 4;

    const int r0 = t >> 2, c0 = (t & 3) * 8;
    const int r1 = (t + 256) >> 2, c1 = ((t + 256) & 3) * 8;

    f32x4 acc[4][4] = {};

    for (int k0 = 0; k0 < CDIM; k0 += BK) {
        gload16(&A[(size_t)(bm + r0) * CDIM + k0 + c0], &lsa[t * 8]);
        gload16(&A[(size_t)(bm + r1) * CDIM + k0 + c1], &lsa[(t + 256) * 8]);
        gload16(&Bw[(size_t)(bnG + r0) * CDIM + k0 + c0], &lsb[t * 8]);
        gload16(&Bw[(size_t)(bnG + r1) * CDIM + k0 + c1], &lsb[(t + 256) * 8]);
        __syncthreads();
        bf16x8 af[4], bfr[4];
        #pragma unroll
        for (int m = 0; m < 4; m++)
            af[m] = *(const bf16x8*)&lsa[(wr + m * 16 + lr) * BK + ks * 8];
        #pragma unroll
        for (int n = 0; n < 4; n++)
            bfr[n] = *(const bf16x8*)&lsb[(wc + n * 16 + lr) * BK + ks * 8];
        #pragma unroll
        for (int m = 0; m < 4; m++)
            #pragma unroll
            for (int n = 0; n < 4; n++)
                acc[m][n] = __builtin_amdgcn_mfma_f32_16x16x32_bf16(af[m], bfr[n], acc[m][n], 0, 0, 0);
        __syncthreads();
    }

    const float* bias = (region == 0) ? bq : (region == 1) ? bk : bv;
    const float scale = (region == 0) ? qscale : 1.f;
    #pragma unroll
    for (int m = 0; m < 4; m++) {
        #pragma unroll
        for (int n = 0; n < 4; n++) {
            const int row0 = bm + wr + m * 16 + ks * 4;
            const int colG = bnG + wc + n * 16 + lr;
            const int cl = colG - region * CDIM;      // local col in [0,512)
            const float bvl = bias[cl];
            #pragma unroll
            for (int r = 0; r < 4; r++) {
                const int rr = row0 + r;
                const float v = (acc[m][n][r] + bvl) * scale;
                if (region == 0) {
                    Qo[(size_t)rr * CDIM + cl] = (bf16)v;
                } else if (region == 1) {
                    Ko[(size_t)rr * CDIM + cl] = (bf16)v;
                } else {
                    const int bb = rr >> 10, nn = rr & 1023;
                    Vto[(size_t)bb * CDIM * NPOS + (size_t)cl * NPOS + nn] = (bf16)v;
                }
            }
        }
    }
}

// ---------------- flash attention ----------------
// 256 blocks (16 batches x 16 q-tiles of 64 rows), 4 waves, each wave 16 q-rows.
// Swapped-QK: S^T = mfma(K,Q) so q = lane&15 is lane-local; online softmax w/
// defer-max THR=8; per-wave LDS P-bounce; K/V staged via gload_lds with
// XOR-swizzled source (chunk c stored at c^(row&7)).
#define QT 64
#define KVB 64

__global__ __launch_bounds__(256, 1) void flash_attn(
    const bf16* __restrict__ Q, const bf16* __restrict__ K,
    const bf16* __restrict__ Vt, bf16* __restrict__ O)
{
    __shared__ __align__(16) bf16 Klds[KVB * CDIM];   // 64 KB [64 kv][512 d]
    __shared__ __align__(16) bf16 Vlds[CDIM * KVB];   // 64 KB [512 d][64 kv]
    __shared__ unsigned int Plds[4][16 * 35];         // per-wave P (u32 pairs, pad 35)

    const int p  = blockIdx.x;
    const int b  = (p & 7) + 8 * ((p >> 3) >> 4);     // XCD-grouped: batch -> XCD
    const int qt = (p >> 3) & 15;

    const int t = threadIdx.x;
    const int lane = t & 63;
    const int w = t >> 6;
    const int lr = lane & 15;
    const int g  = lane >> 4;

    const bf16* Qg = Q  + ((size_t)b * NPOS + qt * QT) * CDIM;
    const bf16* Kg = K  + (size_t)b * NPOS * CDIM;
    const bf16* Vg = Vt + (size_t)b * CDIM * NPOS;

    // Q fragments: wave's 16 rows, B-operand layout (row=lr, k=g*8..)
    bf16x8 qf[16];
    {
        const bf16* qrow = Qg + (size_t)(w * 16 + lr) * CDIM + g * 8;
        #pragma unroll
        for (int ds = 0; ds < 16; ds++)
            qf[ds] = *(const bf16x8*)(qrow + ds * 32);
    }

    f32x4 acc[32];
    #pragma unroll
    for (int i = 0; i < 32; i++) acc[i] = (f32x4){0.f, 0.f, 0.f, 0.f};
    float m_run = -1e30f, l_run = 0.f;
    unsigned int* Pw = Plds[w];

    // stage K tile 0
    #pragma unroll
    for (int i = 0; i < 16; i++) {
        int ci = t + i * 256;
        int r = ci >> 6, c = ci & 63;
        gload16(Kg + (size_t)r * CDIM + ((c ^ (r & 7)) * 8), &Klds[ci * 8]);
    }
    __syncthreads();

    for (int kt = 0; kt < 16; kt++) {
        // stage V(kt) while computing QK^T
        {
            const int kv0 = kt * KVB;
            #pragma unroll
            for (int i = 0; i < 16; i++) {
                int ci = t + i * 256;
                int r = ci >> 3, c = ci & 7;
                gload16(Vg + (size_t)r * NPOS + kv0 + ((c ^ (r & 7)) * 8), &Vlds[ci * 8]);
            }
        }
        // QK^T (swapped): s[k16] = S^T fragment, col q=lr, row kv=g*4+reg
        f32x4 s[4] = {};
        #pragma unroll
        for (int ds = 0; ds < 16; ds++) {
            #pragma unroll
            for (int k16 = 0; k16 < 4; k16++) {
                const int row = k16 * 16 + lr;
                const bf16x8 kf = *(const bf16x8*)&Klds[row * CDIM + (((ds * 4 + g) ^ (row & 7)) * 8)];
                s[k16] = __builtin_amdgcn_mfma_f32_16x16x32_bf16(kf, qf[ds], s[k16], 0, 0, 0);
            }
        }
        // online softmax (defer-max THR=8)
        float mt = -1e30f;
        #pragma unroll
        for (int k16 = 0; k16 < 4; k16++)
            #pragma unroll
            for (int r = 0; r < 4; r++) mt = fmaxf(mt, s[k16][r]);
        mt = fmaxf(mt, __shfl_xor(mt, 16));
        mt = fmaxf(mt, __shfl_xor(mt, 32));
        const float m_new = (mt > m_run + 8.f) ? mt : m_run;
        float pr[16];
        float ts = 0.f;
        #pragma unroll
        for (int k16 = 0; k16 < 4; k16++)
            #pragma unroll
            for (int r = 0; r < 4; r++) {
                float e = __expf(s[k16][r] - m_new);
                pr[k16 * 4 + r] = e; ts += e;
            }
        ts += __shfl_xor(ts, 16);
        ts += __shfl_xor(ts, 32);
        if (__any(m_new != m_run)) {
            const float alpha = __expf(m_run - m_new);
            #pragma unroll
            for (int i = 0; i < 32; i++) {
                acc[i][0] *= alpha; acc[i][1] *= alpha;
                acc[i][2] *= alpha; acc[i][3] *= alpha;
            }
            l_run *= alpha;
        }
        l_run += ts;
        m_run = m_new;
        // pack P -> per-wave LDS: word kv/2 = 8*k16 + 2g (+1)
        #pragma unroll
        for (int k16 = 0; k16 < 4; k16++) {
            Pw[lr * 35 + 8 * k16 + 2 * g + 0] = pk2(pr[k16 * 4 + 0], pr[k16 * 4 + 1]);
            Pw[lr * 35 + 8 * k16 + 2 * g + 1] = pk2(pr[k16 * 4 + 2], pr[k16 * 4 + 3]);
        }
        __syncthreads();                    // V ready; K fully consumed by all waves
        if (kt < 15) {                      // stage K(kt+1) while computing PV
            const int kv0 = (kt + 1) * KVB;
            #pragma unroll
            for (int i = 0; i < 16; i++) {
                int ci = t + i * 256;
                int r = ci >> 6, c = ci & 63;
                gload16(Kg + (size_t)(kv0 + r) * CDIM + ((c ^ (r & 7)) * 8), &Klds[ci * 8]);
            }
        }
        // PV: P fragments (B-operand: row q=lr, k = ks*32 + g*8..)
        bf16x8 pf[2];
        #pragma unroll
        for (int ks2 = 0; ks2 < 2; ks2++) {
            union { unsigned int u[4]; bf16x8 v; } cvt;
            #pragma unroll
            for (int j = 0; j < 4; j++)
                cvt.u[j] = Pw[lr * 35 + ks2 * 16 + g * 4 + j];
            pf[ks2] = cvt.v;
        }
        #pragma unroll
        for (int d16 = 0; d16 < 32; d16++) {
            const int row = d16 * 16 + lr;
            #pragma unroll
            for (int ks2 = 0; ks2 < 2; ks2++) {
                const bf16x8 vf = *(const bf16x8*)&Vlds[row * KVB + (((ks2 * 4 + g) ^ (row & 7)) * 8)];
                acc[d16] = __builtin_amdgcn_mfma_f32_16x16x32_bf16(vf, pf[ks2], acc[d16], 0, 0, 0);
            }
        }
        __syncthreads();                    // K(kt+1) ready; V consumed
    }

    // epilogue: O[q][d] = acc^T / l
    const float inv = 1.f / l_run;
    bf16* Og = O + ((size_t)b * NPOS + qt * QT + w * 16 + lr) * CDIM;
    #pragma unroll
    for (int d16 = 0; d16 < 32; d16++) {
        bf16x4 o;
        o[0] = (bf16)(acc[d16][0] * inv); o[1] = (bf16)(acc[d16][1] * inv);
        o[2] = (bf16)(acc[d16][2] * inv); o[3] = (bf16)(acc[d16][3] * inv);
        *(bf16x4*)(Og + d16 * 16 + g * 4) = o;
    }
}

// ---------------- proj GEMM + bias + residual (f32 out) ----------------
__global__ __launch_bounds__(256) void gemm_proj(
    const bf16* __restrict__ A, const bf16* __restrict__ Bw,
    const float* __restrict__ bias, float* __restrict__ Cp,
    const float* __restrict__ resid)
{
    __shared__ __align__(16) bf16 lsa[BM * BK];
    __shared__ __align__(16) bf16 lsb[BN * BK];
    const int bm = blockIdx.x * BM;
    const int bn = blockIdx.y * BN;
    const int t = threadIdx.x;
    const int lane = t & 63;
    const int wid = t >> 6;
    const int wr = (wid >> 1) * 64;
    const int wc = (wid & 1) * 64;
    const int lr = lane & 15;
    const int ks = lane >> 4;
    const int r0 = t >> 2, c0 = (t & 3) * 8;
    const int r1 = (t + 256) >> 2, c1 = ((t + 256) & 3) * 8;

    f32x4 acc[4][4] = {};
    for (int k0 = 0; k0 < CDIM; k0 += BK) {
        gload16(&A[(size_t)(bm + r0) * CDIM + k0 + c0], &lsa[t * 8]);
        gload16(&A[(size_t)(bm + r1) * CDIM + k0 + c1], &lsa[(t + 256) * 8]);
        gload16(&Bw[(size_t)(bn + r0) * CDIM + k0 + c0], &lsb[t * 8]);
        gload16(&Bw[(size_t)(bn + r1) * CDIM + k0 + c1], &lsb[(t + 256) * 8]);
        __syncthreads();
        bf16x8 af[4], bfr[4];
        #pragma unroll
        for (int m = 0; m < 4; m++)
            af[m] = *(const bf16x8*)&lsa[(wr + m * 16 + lr) * BK + ks * 8];
        #pragma unroll
        for (int n = 0; n < 4; n++)
            bfr[n] = *(const bf16x8*)&lsb[(wc + n * 16 + lr) * BK + ks * 8];
        #pragma unroll
        for (int m = 0; m < 4; m++)
            #pragma unroll
            for (int n = 0; n < 4; n++)
                acc[m][n] = __builtin_amdgcn_mfma_f32_16x16x32_bf16(af[m], bfr[n], acc[m][n], 0, 0, 0);
        __syncthreads();
    }
    #pragma unroll
    for (int m = 0; m < 4; m++) {
        #pragma unroll
        for (int n = 0; n < 4; n++) {
            const int row0 = bm + wr + m * 16 + ks * 4;
            const int col  = bn + wc + n * 16 + lr;
            const float bvl = bias[col];
            #pragma unroll
            for (int r = 0; r < 4; r++) {
                const size_t idx = (size_t)(row0 + r) * CDIM + col;
                Cp[idx] = acc[m][n][r] + bvl + resid[idx];
            }
        }
    }
}

// ---------------- launch ----------------
extern "C" void kernel_launch(void* const* d_in, const int* in_sizes, int n_in,
                              void* d_out, int out_size, void* d_ws, size_t ws_size,
                              hipStream_t stream) {
    const float* x     = (const float*)d_in[0];
    const float* gamma = (const float*)d_in[1];
    const float* beta  = (const float*)d_in[2];
    const float* wq    = (const float*)d_in[3];
    const float* bq    = (const float*)d_in[4];
    const float* wk    = (const float*)d_in[5];
    const float* bk    = (const float*)d_in[6];
    const float* wv    = (const float*)d_in[7];
    const float* bv    = (const float*)d_in[8];
    const float* wp    = (const float*)d_in[9];
    const float* bp    = (const float*)d_in[10];

    char* ws = (char*)d_ws;
    bf16* wt = (bf16*)(ws + OFF_WT);
    bf16* xn = (bf16*)(ws + OFF_XN);
    bf16* Q  = (bf16*)(ws + OFF_Q);
    bf16* Km = (bf16*)(ws + OFF_K);
    bf16* Vt = (bf16*)(ws + OFF_VT);
    bf16* O  = (bf16*)(ws + OFF_O);

    transpose_cast<<<dim3(16, 16, 4), 256, 0, stream>>>(wq, wk, wv, wp, wt);
    groupnorm_kernel<<<dim3(512), 256, 0, stream>>>(x, gamma, beta, xn);

    const float qscale = 0.04419417382415922f;  // 512^-0.5 folded into Q
    gemm_qkv<<<dim3(128, 12), 256, 0, stream>>>(
        xn, wt, bq, bk, bv, qscale, Q, Km, Vt);

    flash_attn<<<dim3(256), 256, 0, stream>>>(Q, Km, Vt, O);

    gemm_proj<<<dim3(128, 4), 256, 0, stream>>>(
        O, wt + (size_t)3 * WELEMS, bp, (float*)d_out, x);
}